// Round 1
// 244.431 us; speedup vs baseline: 1.0076x; 1.0076x over previous
//
#include <hip/hip_runtime.h>

// VQ straight-through: B=32, V=4096, D=64, K=512. N = 131072 rows.
// Outputs (flat, concatenated): z_q_st [N,D] f32, z_q [N,D] f32, indices [N] (as f32).
//
// Correctness contract (established R2/R3, passing): replicate numpy fp32 bitwise —
//  - sums of squares: numpy pairwise_sum scalar 8-accumulator order, products
//    rounded separately (no FMA contraction into the sum)
//  - z@e.T dots: sequential single-accumulator FMA chain over d=0..63 (BLAS)
//  - d2 = fl(fl(A - 2*dot) + C); argmin k-ascending, strict < (first min)
//
// R6 vs R5 (181 us main, VALUBusy 70%, VGPR 40): VGPR_Count=40 proves z[64]
// was NEVER register-resident — LLVM targets 8-waves/EU (~64 VGPR budget) and
// rematerializes the invariant z loads inside the k-loop (16 dwordx4 reloads
// per 4-code group; the R5 per-element "+v" pin didn't stop it). Fix:
//  (a) z loads issued via inline-asm global_load_dwordx4 -> opaque producers,
//      rematerialization is now IMPOSSIBLE (compiler can't see a load);
//  (b) one s_waitcnt vmcnt(0) asm with all 16 vectors tied "+v" -> consumers
//      are data-ordered after the wait and values are laundered once;
//  (c) __launch_bounds__(256, 4): 128-VGPR budget (pressure ~85), 4 waves/EU
//      == today's measured occupancy, so nothing lost;
//  (d) the 2048 in-loop pin asms deleted.
// Numerics bit-identical to R5.

#define VQ_N (32 * 4096)
#define VQ_D 64
#define VQ_K 512

typedef float f32x4 __attribute__((ext_vector_type(4)));

// Rounding barrier: forbids FMA contraction / reassociation through x.
__device__ __forceinline__ float freeze(float x) {
  asm volatile("" : "+v"(x));
  return x;
}

// ---- kernel 1: C_k = np.sum(emb*emb, -1) in numpy fp32 order ----
__global__ __launch_bounds__(256) void vq_norms_kernel(
    const float* __restrict__ emb, float* __restrict__ nrm) {
  int k = blockIdx.x * blockDim.x + threadIdx.x;
  if (k < VQ_K) {
    const float* e = emb + k * VQ_D;
    float r0 = freeze(e[0] * e[0]), r1 = freeze(e[1] * e[1]);
    float r2 = freeze(e[2] * e[2]), r3 = freeze(e[3] * e[3]);
    float r4 = freeze(e[4] * e[4]), r5 = freeze(e[5] * e[5]);
    float r6 = freeze(e[6] * e[6]), r7 = freeze(e[7] * e[7]);
#pragma unroll
    for (int i = 8; i < VQ_D; i += 8) {
      r0 += freeze(e[i + 0] * e[i + 0]); r1 += freeze(e[i + 1] * e[i + 1]);
      r2 += freeze(e[i + 2] * e[i + 2]); r3 += freeze(e[i + 3] * e[i + 3]);
      r4 += freeze(e[i + 4] * e[i + 4]); r5 += freeze(e[i + 5] * e[i + 5]);
      r6 += freeze(e[i + 6] * e[i + 6]); r7 += freeze(e[i + 7] * e[i + 7]);
    }
    nrm[k] = ((r0 + r1) + (r2 + r3)) + ((r4 + r5) + (r6 + r7));
  }
}

// ---- kernel 2: main — 64 rows/block, K split across the 4 waves ----
__global__ __launch_bounds__(256, 4) void vq_main_kernel(
    const float* __restrict__ z_e, const float* __restrict__ emb,
    const float* __restrict__ nrm, float* __restrict__ out_st,
    float* __restrict__ out_q, float* __restrict__ out_idx) {
  __shared__ float s_val[256];  // per (chunk, row) partial best value
  __shared__ int s_idx[256];    // per (chunk, row) partial best index
  __shared__ int s_best[64];    // final best index per row

  const int tid = threadIdx.x;
  const int lane = tid & 63;                                   // row in block
  const int chunk = __builtin_amdgcn_readfirstlane(tid >> 6);  // wave-uniform
  const int row = blockIdx.x * 64 + lane;

  // Row into registers via OPAQUE loads (cannot be rematerialized).
  const float* zp = z_e + (size_t)row * VQ_D;
  f32x4 zv0, zv1, zv2, zv3, zv4, zv5, zv6, zv7;
  f32x4 zv8, zv9, zv10, zv11, zv12, zv13, zv14, zv15;
  asm volatile("global_load_dwordx4 %0, %1, off"             : "=v"(zv0)  : "v"(zp));
  asm volatile("global_load_dwordx4 %0, %1, off offset:16"   : "=v"(zv1)  : "v"(zp));
  asm volatile("global_load_dwordx4 %0, %1, off offset:32"   : "=v"(zv2)  : "v"(zp));
  asm volatile("global_load_dwordx4 %0, %1, off offset:48"   : "=v"(zv3)  : "v"(zp));
  asm volatile("global_load_dwordx4 %0, %1, off offset:64"   : "=v"(zv4)  : "v"(zp));
  asm volatile("global_load_dwordx4 %0, %1, off offset:80"   : "=v"(zv5)  : "v"(zp));
  asm volatile("global_load_dwordx4 %0, %1, off offset:96"   : "=v"(zv6)  : "v"(zp));
  asm volatile("global_load_dwordx4 %0, %1, off offset:112"  : "=v"(zv7)  : "v"(zp));
  asm volatile("global_load_dwordx4 %0, %1, off offset:128"  : "=v"(zv8)  : "v"(zp));
  asm volatile("global_load_dwordx4 %0, %1, off offset:144"  : "=v"(zv9)  : "v"(zp));
  asm volatile("global_load_dwordx4 %0, %1, off offset:160"  : "=v"(zv10) : "v"(zp));
  asm volatile("global_load_dwordx4 %0, %1, off offset:176"  : "=v"(zv11) : "v"(zp));
  asm volatile("global_load_dwordx4 %0, %1, off offset:192"  : "=v"(zv12) : "v"(zp));
  asm volatile("global_load_dwordx4 %0, %1, off offset:208"  : "=v"(zv13) : "v"(zp));
  asm volatile("global_load_dwordx4 %0, %1, off offset:224"  : "=v"(zv14) : "v"(zp));
  asm volatile("global_load_dwordx4 %0, %1, off offset:240"  : "=v"(zv15) : "v"(zp));
  // Single wait; tying every vector as "+v" (1) orders all consumers after the
  // wait via data deps, (2) launders the values through one opaque def.
  asm volatile("s_waitcnt vmcnt(0)"
               : "+v"(zv0), "+v"(zv1), "+v"(zv2), "+v"(zv3),
                 "+v"(zv4), "+v"(zv5), "+v"(zv6), "+v"(zv7),
                 "+v"(zv8), "+v"(zv9), "+v"(zv10), "+v"(zv11),
                 "+v"(zv12), "+v"(zv13), "+v"(zv14), "+v"(zv15));

  float z[VQ_D];
#define VQ_UNPACK(J, V) \
  z[4 * J + 0] = V.x; z[4 * J + 1] = V.y; z[4 * J + 2] = V.z; z[4 * J + 3] = V.w;
  VQ_UNPACK(0, zv0)  VQ_UNPACK(1, zv1)  VQ_UNPACK(2, zv2)  VQ_UNPACK(3, zv3)
  VQ_UNPACK(4, zv4)  VQ_UNPACK(5, zv5)  VQ_UNPACK(6, zv6)  VQ_UNPACK(7, zv7)
  VQ_UNPACK(8, zv8)  VQ_UNPACK(9, zv9)  VQ_UNPACK(10, zv10) VQ_UNPACK(11, zv11)
  VQ_UNPACK(12, zv12) VQ_UNPACK(13, zv13) VQ_UNPACK(14, zv14) VQ_UNPACK(15, zv15)
#undef VQ_UNPACK

  // A = np.sum(z*z) in numpy 8-accumulator order; products rounded separately.
  float r0 = freeze(z[0] * z[0]), r1 = freeze(z[1] * z[1]);
  float r2 = freeze(z[2] * z[2]), r3 = freeze(z[3] * z[3]);
  float r4 = freeze(z[4] * z[4]), r5 = freeze(z[5] * z[5]);
  float r6 = freeze(z[6] * z[6]), r7 = freeze(z[7] * z[7]);
#pragma unroll
  for (int i = 8; i < VQ_D; i += 8) {
    r0 += freeze(z[i + 0] * z[i + 0]); r1 += freeze(z[i + 1] * z[i + 1]);
    r2 += freeze(z[i + 2] * z[i + 2]); r3 += freeze(z[i + 3] * z[i + 3]);
    r4 += freeze(z[i + 4] * z[i + 4]); r5 += freeze(z[i + 5] * z[i + 5]);
    r6 += freeze(z[i + 6] * z[i + 6]); r7 += freeze(z[i + 7] * z[i + 7]);
  }
  const float A = ((r0 + r1) + (r2 + r3)) + ((r4 + r5) + (r6 + r7));

  // Scan this wave's 128 codes, 4 at a time (4 independent FMA chains).
  const int k0 = chunk * (VQ_K / 4);
  float bestv = 3.4e38f;
  int best = k0;
  for (int kk = k0; kk < k0 + VQ_K / 4; kk += 4) {
    const float* e0 = emb + (size_t)(kk + 0) * VQ_D;
    const float* e1 = emb + (size_t)(kk + 1) * VQ_D;
    const float* e2 = emb + (size_t)(kk + 2) * VQ_D;
    const float* e3 = emb + (size_t)(kk + 3) * VQ_D;
    float a0 = 0.f, a1 = 0.f, a2 = 0.f, a3 = 0.f;
#pragma unroll
    for (int d = 0; d < VQ_D; ++d) {
      a0 = fmaf(z[d], e0[d], a0);  // sequential FMA, d ascending (BLAS order)
      a1 = fmaf(z[d], e1[d], a1);
      a2 = fmaf(z[d], e2[d], a2);
      a3 = fmaf(z[d], e3[d], a3);
    }
    // d2 = fl(fl(A - 2*dot) + C); 2*dot exact => fmaf(-2,a,A) == fl(A-2a).
    float t0 = fmaf(-2.0f, a0, A) + nrm[kk + 0];
    float t1 = fmaf(-2.0f, a1, A) + nrm[kk + 1];
    float t2 = fmaf(-2.0f, a2, A) + nrm[kk + 2];
    float t3 = fmaf(-2.0f, a3, A) + nrm[kk + 3];
    if (t0 < bestv) { bestv = t0; best = kk + 0; }
    if (t1 < bestv) { bestv = t1; best = kk + 1; }
    if (t2 < bestv) { bestv = t2; best = kk + 2; }
    if (t3 < bestv) { bestv = t3; best = kk + 3; }
  }

  s_val[chunk * 64 + lane] = bestv;
  s_idx[chunk * 64 + lane] = best;
  __syncthreads();

  // Cross-chunk argmin per row: ascending chunk order + strict < keeps the
  // lowest-index minimum (chunk c's indices all < chunk c+1's) == np.argmin.
  if (tid < 64) {
    float v = s_val[tid];
    int b = s_idx[tid];
#pragma unroll
    for (int c = 1; c < 4; ++c) {
      float vc = s_val[c * 64 + tid];
      if (vc < v) { v = vc; b = s_idx[c * 64 + tid]; }
    }
    s_best[tid] = b;
    out_idx[row] = (float)b;
  }
  __syncthreads();

  // Coalesced output writes: 64 rows x 16 float4 per array.
  const float4* e4 = (const float4*)emb;
  const size_t base4 = (size_t)blockIdx.x * 64 * 16;
  float4* o0 = (float4*)out_st;
  float4* o1 = (float4*)out_q;
#pragma unroll
  for (int t = 0; t < 4; ++t) {
    int i = t * 256 + tid;
    int r = i >> 4, j = i & 15;
    float4 v = e4[s_best[r] * 16 + j];
    o0[base4 + i] = v;
    o1[base4 + i] = v;
  }
}

extern "C" void kernel_launch(void* const* d_in, const int* in_sizes, int n_in,
                              void* d_out, int out_size, void* d_ws,
                              size_t ws_size, hipStream_t stream) {
  const float* z_e = (const float*)d_in[0];  // [N, D] fp32
  const float* emb = (const float*)d_in[1];  // [K, D] fp32
  float* nrm = (float*)d_ws;                 // [K] fp32 scratch

  float* out_st = (float*)d_out;                 // [N, D]
  float* out_q = out_st + (size_t)VQ_N * VQ_D;   // [N, D]
  float* out_idx = out_q + (size_t)VQ_N * VQ_D;  // [N] as float

  vq_norms_kernel<<<(VQ_K + 255) / 256, 256, 0, stream>>>(emb, nrm);
  vq_main_kernel<<<VQ_N / 64, 256, 0, stream>>>(z_e, emb, nrm, out_st, out_q,
                                                out_idx);
}